// Round 12
// baseline (215.694 us; speedup 1.0000x reference)
//
#include <hip/hip_runtime.h>

#define NLEVELS 16
#define TMASK 0xFFFFFu
#define PI2 2654435761u
#define DENSE_TOTAL 711664u   // sum of (R_l+1)^2
#define MASTER 513            // top-level grid width (all levels' coords are subsets)
#define MASTER_TOTAL (513u * 513u)
#define GBLK 258              // ceil(513^2 / 1024)
#define NBUCK 4096            // 64 x 64 spatial buckets
#define NPARTS 256            // sort partitions (1 block each)

typedef float vfloat4 __attribute__((ext_vector_type(4)));     // native vecs for nt ops
typedef float vfloat2 __attribute__((ext_vector_type(2)));
typedef unsigned vuint4 __attribute__((ext_vector_type(4)));

// floor(16 * 1.26^l) for l=0..15, exact fp32 integers, away from boundaries
__constant__ float c_NL[NLEVELS] = {
    16.f, 20.f, 25.f, 32.f, 40.f, 50.f, 64.f, 80.f,
    101.f, 128.f, 161.f, 203.f, 256.f, 322.f, 406.f, 512.f
};

__device__ __forceinline__ unsigned bf16rn(float f) {
    unsigned u = __float_as_uint(f);
    return (u + 0x7FFFu + ((u >> 16) & 1u)) >> 16;   // round-to-nearest-even
}

// ---- pass A (fused, 1024-thread blocks): blocks [0,GBLK) build dense grids
//      (one thread per master (cx,cy); 128B entry read once, all levels emitted);
//      blocks [GBLK,GBLK+NPARTS) histogram with LDS atomics ----
__global__ __launch_bounds__(1024) void build_hist_kernel(
    const float* __restrict__ tb, unsigned* __restrict__ dense,
    const float2* __restrict__ x, unsigned short* __restrict__ h,
    int npts, int chunk)
{
    __shared__ int sh[NBUCK];
    if (blockIdx.x < GBLK) {
        constexpr unsigned kOFF[16] = {0u,289u,730u,1406u,2495u,4176u,6777u,11002u,
            17563u,27967u,44608u,70852u,112468u,178517u,282846u,448495u};
        constexpr unsigned kW[16] = {17u,21u,26u,33u,41u,51u,65u,81u,
            102u,129u,162u,204u,257u,323u,407u,513u};
        unsigned e = blockIdx.x * 1024u + threadIdx.x;
        if (e >= MASTER_TOTAL) return;
        unsigned cy = e / MASTER;
        unsigned cx = e - cy * MASTER;
        unsigned hh = (cx ^ (cy * PI2)) & TMASK;
        float v[32];                                  // full 128 B entry, fully used
        __builtin_memcpy(v, tb + (size_t)hh * 32, 128);
        #pragma unroll
        for (int l = 0; l < 16; ++l) {
            unsigned W = kW[l];
            if (cx < W && cy < W)
                dense[kOFF[l] + cy * W + cx] = bf16rn(v[l]) | (bf16rn(v[16 + l]) << 16);
        }
    } else {
        for (int i = threadIdx.x; i < NBUCK; i += 1024) sh[i] = 0;
        __syncthreads();
        int b = blockIdx.x - GBLK;
        int start = b * chunk;
        int end = min(npts, start + chunk);
        const vfloat2* xv = (const vfloat2*)x;
        for (int i = start + (int)threadIdx.x; i < end; i += 1024) {
            vfloat2 p = __builtin_nontemporal_load(xv + i);
            int bx = min(63, (int)(p.x * 64.f));
            int by = min(63, (int)(p.y * 64.f));
            atomicAdd(&sh[by * 64 + bx], 1);          // LDS atomic
        }
        __syncthreads();
        unsigned short* hb = h + (size_t)b * NBUCK;
        for (int i = threadIdx.x; i < NBUCK; i += 1024)
            hb[i] = (unsigned short)sh[i];            // counts <= chunk=8192
    }
}

// ---- sort B1: per-bin totals across partitions (coalesced) ----
__global__ __launch_bounds__(256) void binsum_kernel(
    const unsigned short* __restrict__ h, int* __restrict__ tot)
{
    int bin = blockIdx.x * 256 + threadIdx.x;
    int acc = 0;
    for (int b = 0; b < NPARTS; ++b) acc += h[(size_t)b * NBUCK + bin];
    tot[bin] = acc;
}

// ---- sort B2: exclusive scan of 4096 bin totals (single block) ----
__global__ __launch_bounds__(1024) void scan_kernel(
    const int* __restrict__ tot, int* __restrict__ base)
{
    __shared__ int s[1024];
    int t = threadIdx.x;
    int v[4], pre[4], sum = 0;
    #pragma unroll
    for (int j = 0; j < 4; ++j) {
        v[j] = tot[t * 4 + j];
        pre[j] = sum;
        sum += v[j];
    }
    s[t] = sum;
    __syncthreads();
    for (int d = 1; d < 1024; d <<= 1) {
        int a = (t >= d) ? s[t - d] : 0;
        __syncthreads();
        s[t] += a;
        __syncthreads();
    }
    int bb = s[t] - sum;   // exclusive prefix of this thread's group
    #pragma unroll
    for (int j = 0; j < 4; ++j)
        base[t * 4 + j] = bb + pre[j];
}

// ---- sort B3: per-(partition,bin) start offsets (coalesced) ----
__global__ __launch_bounds__(256) void binoff_kernel(
    const unsigned short* __restrict__ h, const int* __restrict__ base,
    int* __restrict__ off)
{
    int bin = blockIdx.x * 256 + threadIdx.x;
    int acc = base[bin];
    for (int b = 0; b < NPARTS; ++b) {
        off[(size_t)b * NBUCK + bin] = acc;
        acc += h[(size_t)b * NBUCK + bin];
    }
}

// ---- sort C (1024-thread blocks): scatter packed {x,y,idx} as one nt 16B store ----
__global__ __launch_bounds__(1024) void scatter_part_kernel(
    const float2* __restrict__ x, const int* __restrict__ off,
    vuint4* __restrict__ xsidx, int npts, int chunk)
{
    __shared__ int cnt[NBUCK];
    int b = blockIdx.x;
    const int* ob = off + (size_t)b * NBUCK;
    for (int i = threadIdx.x; i < NBUCK; i += 1024) cnt[i] = ob[i];
    __syncthreads();
    int start = b * chunk;
    int end = min(npts, start + chunk);
    const vfloat2* xv = (const vfloat2*)x;
    for (int i = start + (int)threadIdx.x; i < end; i += 1024) {
        vfloat2 p = __builtin_nontemporal_load(xv + i);
        int bx = min(63, (int)(p.x * 64.f));
        int by = min(63, (int)(p.y * 64.f));
        int pos = atomicAdd(&cnt[by * 64 + bx], 1);   // LDS atomic
        vuint4 rec;
        rec.x = __float_as_uint(p.x); rec.y = __float_as_uint(p.y);
        rec.z = (unsigned)i; rec.w = 0u;
        __builtin_nontemporal_store(rec, xsidx + pos);
    }
}

// ---- pass 2: encode sorted points; paired 8B corner loads; LDS-staged nt writes ----
__global__ __launch_bounds__(256) void encode_sorted_dense_kernel(
    const vuint4* __restrict__ xsidx, const unsigned* __restrict__ dense,
    vfloat4* __restrict__ out, int npts)
{
    constexpr unsigned kOFF[16] = {0u,289u,730u,1406u,2495u,4176u,6777u,11002u,
        17563u,27967u,44608u,70852u,112468u,178517u,282846u,448495u};
    constexpr int kW[16] = {17,21,26,33,41,51,65,81,102,129,162,204,257,323,407,513};

    __shared__ vfloat4 stg[256 * 9];   // [tid][k] with +1 row pad (36 KB)
    __shared__ int soi[256];

    int i = blockIdx.x * 256 + threadIdx.x;
    vfloat4 res[8];
    int oi = -1;
    if (i < npts) {
        vuint4 rec = __builtin_nontemporal_load(xsidx + i);
        float2 p = make_float2(__uint_as_float(rec.x), __uint_as_float(rec.y));
        oi = (int)rec.z;
        #pragma unroll
        for (int g = 0; g < 2; ++g) {
            unsigned long long Hlo[8], Hhi[8];
            float lxv[8], lyv[8];
            #pragma unroll
            for (int k = 0; k < 8; ++k) {
                const int l = g * 8 + k;
                float nl = c_NL[l];
                float fx = p.x * nl;
                float fy = p.y * nl;
                int ix = (int)fx;                 // trunc == floor (x >= 0)
                int iy = (int)fy;
                lxv[k] = fx - (float)ix;
                lyv[k] = fy - (float)iy;
                const unsigned* grid = dense + kOFF[l];
                int b = iy * kW[l] + ix;
                __builtin_memcpy(&Hlo[k], grid + b, 8);          // corners (0,0),(1,0)
                __builtin_memcpy(&Hhi[k], grid + b + kW[l], 8);  // corners (0,1),(1,1)
            }
            #pragma unroll
            for (int k = 0; k < 8; k += 2) {
                float r[4];
                #pragma unroll
                for (int m = 0; m < 2; ++m) {
                    float lx = lxv[k + m], ly = lyv[k + m];
                    float w0 = (1.f - lx) * (1.f - ly);
                    float w1 = lx * (1.f - ly);
                    float w2 = (1.f - lx) * ly;
                    float w3 = lx * ly;
                    unsigned u0 = (unsigned)Hlo[k + m];
                    unsigned u1 = (unsigned)(Hlo[k + m] >> 32);
                    unsigned u2 = (unsigned)Hhi[k + m];
                    unsigned u3 = (unsigned)(Hhi[k + m] >> 32);
                    float a0 = __uint_as_float(u0 << 16), b0 = __uint_as_float(u0 & 0xFFFF0000u);
                    float a1 = __uint_as_float(u1 << 16), b1 = __uint_as_float(u1 & 0xFFFF0000u);
                    float a2 = __uint_as_float(u2 << 16), b2 = __uint_as_float(u2 & 0xFFFF0000u);
                    float a3 = __uint_as_float(u3 << 16), b3 = __uint_as_float(u3 & 0xFFFF0000u);
                    r[2*m]   = w0*a0 + w1*a1 + w2*a2 + w3*a3;
                    r[2*m+1] = w0*b0 + w1*b1 + w2*b2 + w3*b3;
                }
                vfloat4 v; v.x = r[0]; v.y = r[1]; v.z = r[2]; v.w = r[3];
                res[g * 4 + (k >> 1)] = v;
            }
        }
    } else {
        #pragma unroll
        for (int k = 0; k < 8; ++k) res[k] = (vfloat4)(0.f);
    }

    soi[threadIdx.x] = oi;
    #pragma unroll
    for (int k = 0; k < 8; ++k) stg[threadIdx.x * 9 + k] = res[k];
    __syncthreads();

    // 8 lanes per output row: each store instruction writes full 64-B lines
    int r0 = threadIdx.x >> 3;    // 0..31
    int j  = threadIdx.x & 7;
    #pragma unroll
    for (int p = 0; p < 8; ++p) {
        int row = p * 32 + r0;
        int o = soi[row];
        if (o >= 0)
            __builtin_nontemporal_store(stg[row * 9 + j], out + (size_t)o * 8 + j);
    }
}

// ---- fallback (round-1 kernel) if ws is too small ----
__global__ __launch_bounds__(256) void hashgrid_kernel(
    const float2* __restrict__ x, const float* __restrict__ tb,
    float2* __restrict__ out, int npts)
{
    int tid = blockIdx.x * blockDim.x + threadIdx.x;
    int n = tid >> 4;
    int l = tid & 15;
    if (n >= npts) return;

    float2 xy = x[n];
    float nl = c_NL[l];
    float fx = xy.x * nl;
    float fy = xy.y * nl;
    int ixi = (int)fx;
    int iyi = (int)fy;
    float lx = fx - (float)ixi;
    float ly = fy - (float)iyi;
    unsigned ix = (unsigned)ixi, iy = (unsigned)iyi;

    unsigned hy0 = iy * PI2;
    unsigned hy1 = (iy + 1u) * PI2;
    unsigned h0 = (ix        ^ hy0) & TMASK;
    unsigned h1 = ((ix + 1u) ^ hy0) & TMASK;
    unsigned h2 = (ix        ^ hy1) & TMASK;
    unsigned h3 = ((ix + 1u) ^ hy1) & TMASK;

    const float* p0 = tb + ((size_t)h0 * 32 + l);
    const float* p1 = tb + ((size_t)h1 * 32 + l);
    const float* p2 = tb + ((size_t)h2 * 32 + l);
    const float* p3 = tb + ((size_t)h3 * 32 + l);
    float a0 = p0[0], b0 = p0[16];
    float a1 = p1[0], b1 = p1[16];
    float a2 = p2[0], b2 = p2[16];
    float a3 = p3[0], b3 = p3[16];

    float w0 = (1.f - lx) * (1.f - ly);
    float w1 = lx * (1.f - ly);
    float w2 = (1.f - lx) * ly;
    float w3 = lx * ly;
    float o0 = w0 * a0 + w1 * a1 + w2 * a2 + w3 * a3;
    float o1 = w0 * b0 + w1 * b1 + w2 * b2 + w3 * b3;

    out[(size_t)n * NLEVELS + l] = make_float2(o0, o1);
}

extern "C" void kernel_launch(void* const* d_in, const int* in_sizes, int n_in,
                              void* d_out, int out_size, void* d_ws, size_t ws_size,
                              hipStream_t stream) {
    const float2* x = (const float2*)d_in[0];
    const float* tb = (const float*)d_in[1];
    int npts = in_sizes[0] / 2;

    // ws layout (256-B aligned): dense | xsidx | h(u16) | tot | base | off
    size_t dense_bytes = ((size_t)DENSE_TOTAL * 4 + 255) & ~(size_t)255;
    size_t xsidx_off   = dense_bytes;
    size_t xsidx_bytes = ((size_t)npts * 16 + 255) & ~(size_t)255;
    size_t h_off       = xsidx_off + xsidx_bytes;
    size_t h_bytes     = ((size_t)NPARTS * NBUCK * 2 + 255) & ~(size_t)255;  // 2 MiB
    size_t tot_off     = h_off + h_bytes;
    size_t tot_bytes   = NBUCK * 4;
    size_t base_off    = tot_off + tot_bytes;
    size_t off_off     = base_off + tot_bytes;
    size_t need        = off_off + (size_t)NPARTS * NBUCK * 4;

    if (ws_size >= need) {
        char* ws = (char*)d_ws;
        unsigned* dense = (unsigned*)ws;
        vuint4* xsidx   = (vuint4*)(ws + xsidx_off);
        unsigned short* h = (unsigned short*)(ws + h_off);
        int* tot        = (int*)(ws + tot_off);
        int* base       = (int*)(ws + base_off);
        int* off        = (int*)(ws + off_off);

        int chunk = (npts + NPARTS - 1) / NPARTS;
        int nblk = (npts + 255) / 256;

        build_hist_kernel<<<GBLK + NPARTS, 1024, 0, stream>>>(tb, dense, x, h, npts, chunk);
        binsum_kernel<<<NBUCK / 256, 256, 0, stream>>>(h, tot);
        scan_kernel<<<1, 1024, 0, stream>>>(tot, base);
        binoff_kernel<<<NBUCK / 256, 256, 0, stream>>>(h, base, off);
        scatter_part_kernel<<<NPARTS, 1024, 0, stream>>>(x, off, xsidx, npts, chunk);
        encode_sorted_dense_kernel<<<nblk, 256, 0, stream>>>(
            xsidx, dense, (vfloat4*)d_out, npts);
    } else {
        long long total = (long long)npts * NLEVELS;
        long long grid = (total + 255) / 256;
        hashgrid_kernel<<<(int)grid, 256, 0, stream>>>(x, tb, (float2*)d_out, npts);
    }
}

// Round 13
// 128.667 us; speedup vs baseline: 1.6764x; 1.6764x over previous
//
#include <hip/hip_runtime.h>

#define NLEVELS 16
#define TMASK 0xFFFFFu
#define PI2 2654435761u
#define DENSE_TOTAL 711664u   // sum of (R_l+1)^2
#define MASTER 513            // top-level grid width (all levels' coords are subsets)
#define MASTER_TOTAL (513u * 513u)
#define GBLK 1029             // ceil(513^2 / 256)
#define NBUCK 4096            // 64 x 64 spatial buckets
#define NPARTS 256            // sort partitions (1 block each)

typedef float vfloat4 __attribute__((ext_vector_type(4)));   // native vec for nt-store

// floor(16 * 1.26^l) for l=0..15, exact fp32 integers, away from boundaries
__constant__ float c_NL[NLEVELS] = {
    16.f, 20.f, 25.f, 32.f, 40.f, 50.f, 64.f, 80.f,
    101.f, 128.f, 161.f, 203.f, 256.f, 322.f, 406.f, 512.f
};

__device__ __forceinline__ unsigned bf16rn(float f) {
    unsigned u = __float_as_uint(f);
    return (u + 0x7FFFu + ((u >> 16) & 1u)) >> 16;   // round-to-nearest-even
}

// ---- pass A (fused): blocks [0,GBLK) build dense grids (one thread per master
//      (cx,cy); entry line read ONCE, all levels emitted); [GBLK,GBLK+NPARTS) histogram ----
__global__ __launch_bounds__(256) void build_hist_kernel(
    const float* __restrict__ tb, unsigned* __restrict__ dense,
    const float2* __restrict__ x, unsigned short* __restrict__ h,
    int npts, int chunk)
{
    __shared__ int sh[NBUCK];
    if (blockIdx.x < GBLK) {
        constexpr unsigned kOFF[16] = {0u,289u,730u,1406u,2495u,4176u,6777u,11002u,
            17563u,27967u,44608u,70852u,112468u,178517u,282846u,448495u};
        constexpr unsigned kW[16] = {17u,21u,26u,33u,41u,51u,65u,81u,
            102u,129u,162u,204u,257u,323u,407u,513u};
        unsigned e = blockIdx.x * 256u + threadIdx.x;
        if (e >= MASTER_TOTAL) return;
        unsigned cy = e / MASTER;
        unsigned cx = e - cy * MASTER;
        unsigned hh = (cx ^ (cy * PI2)) & TMASK;
        float v[32];                                  // full 128 B entry, fully used
        __builtin_memcpy(v, tb + (size_t)hh * 32, 128);
        #pragma unroll
        for (int l = 0; l < 16; ++l) {
            unsigned W = kW[l];
            if (cx < W && cy < W)
                dense[kOFF[l] + cy * W + cx] = bf16rn(v[l]) | (bf16rn(v[16 + l]) << 16);
        }
    } else {
        for (int i = threadIdx.x; i < NBUCK; i += 256) sh[i] = 0;
        __syncthreads();
        int b = blockIdx.x - GBLK;
        int start = b * chunk;
        int end = min(npts, start + chunk);
        for (int i = start + (int)threadIdx.x; i < end; i += 256) {
            float2 p = x[i];
            int bx = min(63, (int)(p.x * 64.f));
            int by = min(63, (int)(p.y * 64.f));
            atomicAdd(&sh[by * 64 + bx], 1);          // LDS atomic
        }
        __syncthreads();
        unsigned short* hb = h + (size_t)b * NBUCK;
        for (int i = threadIdx.x; i < NBUCK; i += 256)
            hb[i] = (unsigned short)sh[i];            // counts <= chunk=8192
    }
}

// ---- sort B1: per-bin totals across partitions (coalesced) ----
__global__ __launch_bounds__(256) void binsum_kernel(
    const unsigned short* __restrict__ h, int* __restrict__ tot)
{
    int bin = blockIdx.x * 256 + threadIdx.x;
    int acc = 0;
    for (int b = 0; b < NPARTS; ++b) acc += h[(size_t)b * NBUCK + bin];
    tot[bin] = acc;
}

// ---- sort B2: exclusive scan of 4096 bin totals (single block) ----
__global__ __launch_bounds__(1024) void scan_kernel(
    const int* __restrict__ tot, int* __restrict__ base)
{
    __shared__ int s[1024];
    int t = threadIdx.x;
    int v[4], pre[4], sum = 0;
    #pragma unroll
    for (int j = 0; j < 4; ++j) {
        v[j] = tot[t * 4 + j];
        pre[j] = sum;
        sum += v[j];
    }
    s[t] = sum;
    __syncthreads();
    for (int d = 1; d < 1024; d <<= 1) {
        int a = (t >= d) ? s[t - d] : 0;
        __syncthreads();
        s[t] += a;
        __syncthreads();
    }
    int bb = s[t] - sum;   // exclusive prefix of this thread's group
    #pragma unroll
    for (int j = 0; j < 4; ++j)
        base[t * 4 + j] = bb + pre[j];
}

// ---- sort B3: per-(partition,bin) start offsets (coalesced) ----
__global__ __launch_bounds__(256) void binoff_kernel(
    const unsigned short* __restrict__ h, const int* __restrict__ base,
    int* __restrict__ off)
{
    int bin = blockIdx.x * 256 + threadIdx.x;
    int acc = base[bin];
    for (int b = 0; b < NPARTS; ++b) {
        off[(size_t)b * NBUCK + bin] = acc;
        acc += h[(size_t)b * NBUCK + bin];
    }
}

// ---- sort C: scatter packed {x,y,idx} as one aligned 16B store ----
__global__ __launch_bounds__(256) void scatter_part_kernel(
    const float2* __restrict__ x, const int* __restrict__ off,
    uint4* __restrict__ xsidx, int npts, int chunk)
{
    __shared__ int cnt[NBUCK];
    int b = blockIdx.x;
    const int* ob = off + (size_t)b * NBUCK;
    for (int i = threadIdx.x; i < NBUCK; i += 256) cnt[i] = ob[i];
    __syncthreads();
    int start = b * chunk;
    int end = min(npts, start + chunk);
    for (int i = start + (int)threadIdx.x; i < end; i += 256) {
        float2 p = x[i];
        int bx = min(63, (int)(p.x * 64.f));
        int by = min(63, (int)(p.y * 64.f));
        int pos = atomicAdd(&cnt[by * 64 + bx], 1);   // LDS atomic
        xsidx[pos] = make_uint4(__float_as_uint(p.x), __float_as_uint(p.y),
                                (unsigned)i, 0u);
    }
}

// ---- pass 2: encode sorted points; paired 8B corner loads; LDS-staged nt writes ----
__global__ __launch_bounds__(256) void encode_sorted_dense_kernel(
    const uint4* __restrict__ xsidx, const unsigned* __restrict__ dense,
    vfloat4* __restrict__ out, int npts)
{
    constexpr unsigned kOFF[16] = {0u,289u,730u,1406u,2495u,4176u,6777u,11002u,
        17563u,27967u,44608u,70852u,112468u,178517u,282846u,448495u};
    constexpr int kW[16] = {17,21,26,33,41,51,65,81,102,129,162,204,257,323,407,513};

    __shared__ vfloat4 stg[256 * 9];   // [tid][k] with +1 row pad (36 KB)
    __shared__ int soi[256];

    int i = blockIdx.x * 256 + threadIdx.x;
    vfloat4 res[8];
    int oi = -1;
    if (i < npts) {
        uint4 rec = xsidx[i];
        float2 p = make_float2(__uint_as_float(rec.x), __uint_as_float(rec.y));
        oi = (int)rec.z;
        #pragma unroll
        for (int g = 0; g < 2; ++g) {
            unsigned long long Hlo[8], Hhi[8];
            float lxv[8], lyv[8];
            #pragma unroll
            for (int k = 0; k < 8; ++k) {
                const int l = g * 8 + k;
                float nl = c_NL[l];
                float fx = p.x * nl;
                float fy = p.y * nl;
                int ix = (int)fx;                 // trunc == floor (x >= 0)
                int iy = (int)fy;
                lxv[k] = fx - (float)ix;
                lyv[k] = fy - (float)iy;
                const unsigned* grid = dense + kOFF[l];
                int b = iy * kW[l] + ix;
                __builtin_memcpy(&Hlo[k], grid + b, 8);          // corners (0,0),(1,0)
                __builtin_memcpy(&Hhi[k], grid + b + kW[l], 8);  // corners (0,1),(1,1)
            }
            #pragma unroll
            for (int k = 0; k < 8; k += 2) {
                float r[4];
                #pragma unroll
                for (int m = 0; m < 2; ++m) {
                    float lx = lxv[k + m], ly = lyv[k + m];
                    float w0 = (1.f - lx) * (1.f - ly);
                    float w1 = lx * (1.f - ly);
                    float w2 = (1.f - lx) * ly;
                    float w3 = lx * ly;
                    unsigned u0 = (unsigned)Hlo[k + m];
                    unsigned u1 = (unsigned)(Hlo[k + m] >> 32);
                    unsigned u2 = (unsigned)Hhi[k + m];
                    unsigned u3 = (unsigned)(Hhi[k + m] >> 32);
                    float a0 = __uint_as_float(u0 << 16), b0 = __uint_as_float(u0 & 0xFFFF0000u);
                    float a1 = __uint_as_float(u1 << 16), b1 = __uint_as_float(u1 & 0xFFFF0000u);
                    float a2 = __uint_as_float(u2 << 16), b2 = __uint_as_float(u2 & 0xFFFF0000u);
                    float a3 = __uint_as_float(u3 << 16), b3 = __uint_as_float(u3 & 0xFFFF0000u);
                    r[2*m]   = w0*a0 + w1*a1 + w2*a2 + w3*a3;
                    r[2*m+1] = w0*b0 + w1*b1 + w2*b2 + w3*b3;
                }
                vfloat4 v; v.x = r[0]; v.y = r[1]; v.z = r[2]; v.w = r[3];
                res[g * 4 + (k >> 1)] = v;
            }
        }
    } else {
        #pragma unroll
        for (int k = 0; k < 8; ++k) res[k] = (vfloat4)(0.f);
    }

    soi[threadIdx.x] = oi;
    #pragma unroll
    for (int k = 0; k < 8; ++k) stg[threadIdx.x * 9 + k] = res[k];
    __syncthreads();

    // 8 lanes per output row: each store instruction writes full 64-B lines
    int r0 = threadIdx.x >> 3;    // 0..31
    int j  = threadIdx.x & 7;
    #pragma unroll
    for (int p = 0; p < 8; ++p) {
        int row = p * 32 + r0;
        int o = soi[row];
        if (o >= 0)
            __builtin_nontemporal_store(stg[row * 9 + j], out + (size_t)o * 8 + j);
    }
}

// ---- fallback (round-1 kernel) if ws is too small ----
__global__ __launch_bounds__(256) void hashgrid_kernel(
    const float2* __restrict__ x, const float* __restrict__ tb,
    float2* __restrict__ out, int npts)
{
    int tid = blockIdx.x * blockDim.x + threadIdx.x;
    int n = tid >> 4;
    int l = tid & 15;
    if (n >= npts) return;

    float2 xy = x[n];
    float nl = c_NL[l];
    float fx = xy.x * nl;
    float fy = xy.y * nl;
    int ixi = (int)fx;
    int iyi = (int)fy;
    float lx = fx - (float)ixi;
    float ly = fy - (float)iyi;
    unsigned ix = (unsigned)ixi, iy = (unsigned)iyi;

    unsigned hy0 = iy * PI2;
    unsigned hy1 = (iy + 1u) * PI2;
    unsigned h0 = (ix        ^ hy0) & TMASK;
    unsigned h1 = ((ix + 1u) ^ hy0) & TMASK;
    unsigned h2 = (ix        ^ hy1) & TMASK;
    unsigned h3 = ((ix + 1u) ^ hy1) & TMASK;

    const float* p0 = tb + ((size_t)h0 * 32 + l);
    const float* p1 = tb + ((size_t)h1 * 32 + l);
    const float* p2 = tb + ((size_t)h2 * 32 + l);
    const float* p3 = tb + ((size_t)h3 * 32 + l);
    float a0 = p0[0], b0 = p0[16];
    float a1 = p1[0], b1 = p1[16];
    float a2 = p2[0], b2 = p2[16];
    float a3 = p3[0], b3 = p3[16];

    float w0 = (1.f - lx) * (1.f - ly);
    float w1 = lx * (1.f - ly);
    float w2 = (1.f - lx) * ly;
    float w3 = lx * ly;
    float o0 = w0 * a0 + w1 * a1 + w2 * a2 + w3 * a3;
    float o1 = w0 * b0 + w1 * b1 + w2 * b2 + w3 * b3;

    out[(size_t)n * NLEVELS + l] = make_float2(o0, o1);
}

extern "C" void kernel_launch(void* const* d_in, const int* in_sizes, int n_in,
                              void* d_out, int out_size, void* d_ws, size_t ws_size,
                              hipStream_t stream) {
    const float2* x = (const float2*)d_in[0];
    const float* tb = (const float*)d_in[1];
    int npts = in_sizes[0] / 2;

    // ws layout (256-B aligned): dense | xsidx | h(u16) | tot | base | off
    size_t dense_bytes = ((size_t)DENSE_TOTAL * 4 + 255) & ~(size_t)255;
    size_t xsidx_off   = dense_bytes;
    size_t xsidx_bytes = ((size_t)npts * 16 + 255) & ~(size_t)255;
    size_t h_off       = xsidx_off + xsidx_bytes;
    size_t h_bytes     = ((size_t)NPARTS * NBUCK * 2 + 255) & ~(size_t)255;  // 2 MiB
    size_t tot_off     = h_off + h_bytes;
    size_t tot_bytes   = NBUCK * 4;
    size_t base_off    = tot_off + tot_bytes;
    size_t off_off     = base_off + tot_bytes;
    size_t need        = off_off + (size_t)NPARTS * NBUCK * 4;

    if (ws_size >= need) {
        char* ws = (char*)d_ws;
        unsigned* dense = (unsigned*)ws;
        uint4* xsidx    = (uint4*)(ws + xsidx_off);
        unsigned short* h = (unsigned short*)(ws + h_off);
        int* tot        = (int*)(ws + tot_off);
        int* base       = (int*)(ws + base_off);
        int* off        = (int*)(ws + off_off);

        int chunk = (npts + NPARTS - 1) / NPARTS;
        int nblk = (npts + 255) / 256;

        build_hist_kernel<<<GBLK + NPARTS, 256, 0, stream>>>(tb, dense, x, h, npts, chunk);
        binsum_kernel<<<NBUCK / 256, 256, 0, stream>>>(h, tot);
        scan_kernel<<<1, 1024, 0, stream>>>(tot, base);
        binoff_kernel<<<NBUCK / 256, 256, 0, stream>>>(h, base, off);
        scatter_part_kernel<<<NPARTS, 256, 0, stream>>>(x, off, xsidx, npts, chunk);
        encode_sorted_dense_kernel<<<nblk, 256, 0, stream>>>(
            xsidx, dense, (vfloat4*)d_out, npts);
    } else {
        long long total = (long long)npts * NLEVELS;
        long long grid = (total + 255) / 256;
        hashgrid_kernel<<<(int)grid, 256, 0, stream>>>(x, tb, (float2*)d_out, npts);
    }
}